// Round 9
// baseline (442.461 us; speedup 1.0000x reference)
//
#include <hip/hip_runtime.h>
#include <hip/hip_bf16.h>

// Capsule routing, 2 dispatches:
//   prep_k : x fp32 -> bf16 pre-swizzled 128-row chunks (xs) + colsum partials Sp
//   route_k: one block per batch; both routing iters + final squash fully
//            in-block (y/o/w~ never leave LDS). 2 teams x 4 waves.
//   b[c,n] = x[n,:]·w~[c,:],  w~[c,k] = sum_d o[c,d] W[k,c*16+d]
//   y[c,k] = sum_n softmax_c(b)[c,n] x[n,k],  o = squash(y[c,:]·W_c)

#define SEQ 2048
#define KD  128

typedef __attribute__((ext_vector_type(8))) short bf16x8;
typedef __attribute__((ext_vector_type(4))) float f32x4;

__device__ __forceinline__ short f2bf(float f) {
  unsigned u = __float_as_uint(f);
  u = u + 0x7fffu + ((u >> 16) & 1u);   // RNE
  return (short)(u >> 16);
}
// lx swizzle: rows 8/16/24 apart land in distinct 32B windows (GEMM2 gather 2-way)
__device__ __forceinline__ int swz(int row) {
  return ((row & 7) << 4) ^ ((row & 24) << 2);
}

// ---- prep: x fp32 -> bf16 pre-swizzled 128-row chunks + colsum partial ----
__global__ __launch_bounds__(256) void prep_k(const float* __restrict__ x,
                                              short* __restrict__ xs,
                                              float* __restrict__ Sp) {
  int blk = blockIdx.x;                 // 2048 chunks of 128 rows
  int t = threadIdx.x, oct = t & 15, rsub = t >> 4;
  size_t row0 = (size_t)blk * 128;
  char* dst = (char*)xs + (size_t)blk * 32768;
  float sac[8] = {0.f,0.f,0.f,0.f,0.f,0.f,0.f,0.f};
  #pragma unroll
  for (int sub = 0; sub < 8; ++sub) {
    int r = sub * 16 + rsub;
    const float* gp = x + (row0 + r) * KD + oct * 8;
    float4 f0 = *(const float4*)gp, f1 = *(const float4*)(gp + 4);
    bf16x8 v; short* vp = (short*)&v;
    vp[0] = f2bf(f0.x); vp[1] = f2bf(f0.y); vp[2] = f2bf(f0.z); vp[3] = f2bf(f0.w);
    vp[4] = f2bf(f1.x); vp[5] = f2bf(f1.y); vp[6] = f2bf(f1.z); vp[7] = f2bf(f1.w);
    sac[0] += f0.x; sac[1] += f0.y; sac[2] += f0.z; sac[3] += f0.w;
    sac[4] += f1.x; sac[5] += f1.y; sac[6] += f1.z; sac[7] += f1.w;
    *(bf16x8*)(dst + ((r * 256 + oct * 16) ^ swz(r))) = v;
  }
  __shared__ float red[2048];           // [rsub][k]
  float4* rp = (float4*)&red[rsub * 128 + oct * 8];
  rp[0] = make_float4(sac[0], sac[1], sac[2], sac[3]);
  rp[1] = make_float4(sac[4], sac[5], sac[6], sac[7]);
  __syncthreads();
  if (t < 128) {
    float s = 0.f;
    #pragma unroll
    for (int i = 0; i < 16; ++i) s += red[i * 128 + t];
    Sp[blk * KD + t] = s;               // plain partial store, no atomics
  }
}

// ---- route: whole batch per block; 512 thr = 2 teams x 4 waves ----
__global__ __launch_bounds__(512, 1) void route_k(const short* __restrict__ xs,
                                                  const float* __restrict__ W,
                                                  const float* __restrict__ Sp,
                                                  float* __restrict__ out) {
  __shared__ char ldsbuf[90112];        // 88KB
  int b = blockIdx.x;                   // 128 batches
  int t = threadIdx.x;
  int wv = t >> 6, tm = wv >> 2, w4 = wv & 3;
  int lane = t & 63, l15 = lane & 15, lg = lane >> 4;
  int tt = t & 255;                     // team-local thread id

  char* lx  = ldsbuf + tm * 40960;              // 32KB per team, swizzled x chunk
  char* lcn = ldsbuf + tm * 40960 + 32768;      // 8KB per team, cn^T bf16
  char* lw  = ldsbuf + 81920;                   // 8KB shared, w~ bf16
  float* yv   = (float*)ldsbuf;                 // 16KB y (32x128) — aliases lx(team0)
  float* sarr = (float*)(ldsbuf + 16384);       // 2KB s (32x16)
  float* olds = (float*)(ldsbuf + 18432);       // 2KB o (32x16)

  f32x4 zz = {0.f, 0.f, 0.f, 0.f};

  for (int iter = 0; iter < 2; ++iter) {
    // ---------- prologue: yv -> s -> o -> w~ (all in LDS) ----------
    if (iter == 0) {
      if (t < 128) {                    // uniform-c iter0: y = colsum/32
        float s = 0.f;
        #pragma unroll
        for (int j = 0; j < 16; ++j) s += Sp[(b * 16 + j) * KD + t];
        sarr[t] = s * (1.f / 32.f);
      }
      __syncthreads();
      #pragma unroll
      for (int i = 0; i < 8; ++i) { int idx = i * 512 + t; yv[idx] = sarr[idx & 127]; }
      __syncthreads();
    }
    // else: yv already holds reduced y from iter0's epilogue (barrier'd)

    float sreg;
    {   // s[c,d] = y[c,:]·W[:,c*16+d], one (c,d) per thread
      int c = t >> 4, d = t & 15;
      float acc = 0.f;
      #pragma unroll 8
      for (int k = 0; k < KD; ++k) acc += yv[c * KD + k] * W[k * 512 + c * 16 + d];
      sreg = acc;
    }
    sarr[t] = sreg;                     // disjoint from yv
    __syncthreads();
    {   // squash per capsule
      int c = t >> 4;
      float s2 = 1e-7f;
      #pragma unroll
      for (int dd = 0; dd < 16; ++dd) { float v = sarr[c * 16 + dd]; s2 += v * v; }
      olds[t] = (sqrtf(s2) / (0.5f + s2)) * sreg;
    }
    __syncthreads();
    #pragma unroll
    for (int i = 0; i < 8; ++i) {       // w~[c,k] -> lw bf16 swizzled
      int idx = i * 512 + t, c = idx >> 7, k = idx & 127;
      float acc = 0.f;
      #pragma unroll
      for (int dd = 0; dd < 16; ++dd) acc += olds[c * 16 + dd] * W[k * 512 + c * 16 + dd];
      *(short*)(lw + ((c * 256 + k * 2) ^ ((c & 7) << 4))) = f2bf(acc);
    }
    __syncthreads();

    // ---------- main loop: 8 steps, team tm handles chunk step*2+tm ----------
    f32x4 yacc[2][8];
    #pragma unroll
    for (int i = 0; i < 2; ++i)
      #pragma unroll
      for (int j = 0; j < 8; ++j) yacc[i][j] = zz;

    for (int step = 0; step < 8; ++step) {
      {   // stage pre-swizzled bf16 chunk (pure 16B copies, team-local)
        int ch = step * 2 + tm;
        const char* gs = (const char*)xs + ((size_t)b * 16 + ch) * 32768;
        #pragma unroll
        for (int sub = 0; sub < 8; ++sub) {
          int off = sub * 4096 + tt * 16;
          *(bf16x8*)(lx + off) = *(const bf16x8*)(gs + off);
        }
      }
      __syncthreads();

      // GEMM1: scores; wave w4 owns rows [w4*32, w4*32+32)
      f32x4 sc[2][2];
      sc[0][0] = zz; sc[0][1] = zz; sc[1][0] = zz; sc[1][1] = zz;
      #pragma unroll
      for (int ks = 0; ks < 4; ++ks) {
        bf16x8 a[2], bw[2];
        #pragma unroll
        for (int mi = 0; mi < 2; ++mi) {
          int row = w4 * 32 + mi * 16 + l15;
          a[mi] = *(const bf16x8*)(lx + ((row * 256 + ks * 64 + lg * 16) ^ swz(row)));
        }
        #pragma unroll
        for (int ct = 0; ct < 2; ++ct) {
          int cc = ct * 16 + l15;
          bw[ct] = *(const bf16x8*)(lw + ((cc * 256 + ks * 64 + lg * 16) ^ ((cc & 7) << 4)));
        }
        #pragma unroll
        for (int mi = 0; mi < 2; ++mi)
          #pragma unroll
          for (int ct = 0; ct < 2; ++ct)
            sc[mi][ct] = __builtin_amdgcn_mfma_f32_16x16x32_bf16(a[mi], bw[ct], sc[mi][ct], 0, 0, 0);
      }

      // softmax over 32 capsules per row; write cn^T to team lcn
      #pragma unroll
      for (int mi = 0; mi < 2; ++mi) {
        #pragma unroll
        for (int r = 0; r < 4; ++r) {
          float v0 = sc[mi][0][r], v1 = sc[mi][1][r];
          float mx = fmaxf(v0, v1);
          mx = fmaxf(mx, __shfl_xor(mx, 1));
          mx = fmaxf(mx, __shfl_xor(mx, 2));
          mx = fmaxf(mx, __shfl_xor(mx, 4));
          mx = fmaxf(mx, __shfl_xor(mx, 8));
          float e0 = __expf(v0 - mx), e1 = __expf(v1 - mx);
          float sm = e0 + e1;
          sm += __shfl_xor(sm, 1); sm += __shfl_xor(sm, 2);
          sm += __shfl_xor(sm, 4); sm += __shfl_xor(sm, 8);
          float inv = 1.f / sm;
          int row = w4 * 32 + mi * 16 + lg * 4 + r;
          int c0 = l15, c1 = 16 + l15;
          *(short*)(lcn + ((c0 * 256 + row * 2) ^ ((c0 & 7) << 4))) = f2bf(e0 * inv);
          *(short*)(lcn + ((c1 * 256 + row * 2) ^ ((c1 & 7) << 4))) = f2bf(e1 * inv);
        }
      }
      __syncthreads();

      // GEMM2: y += cn^T @ x; wave w4 contracts rows [w4*32, w4*32+32)
      {
        bf16x8 a2[2];
        #pragma unroll
        for (int m2 = 0; m2 < 2; ++m2) {
          int cc = m2 * 16 + l15;
          a2[m2] = *(const bf16x8*)(lcn + ((cc * 256 + w4 * 64 + lg * 16) ^ ((cc & 7) << 4)));
        }
        #pragma unroll
        for (int nt = 0; nt < 8; ++nt) {
          bf16x8 bx;
          short* bp = (short*)&bx;
          int col = nt * 16 + l15;
          int rbase = w4 * 32 + lg * 8;
          #pragma unroll
          for (int j = 0; j < 8; ++j) {
            int row = rbase + j;
            bp[j] = *(const short*)(lx + ((row * 256 + col * 2) ^ swz(row)));
          }
          yacc[0][nt] = __builtin_amdgcn_mfma_f32_16x16x32_bf16(a2[0], bx, yacc[0][nt], 0, 0, 0);
          yacc[1][nt] = __builtin_amdgcn_mfma_f32_16x16x32_bf16(a2[1], bx, yacc[1][nt], 0, 0, 0);
        }
      }
      __syncthreads();
    }

    // ---------- reduce all 8 waves' partials into yv (aliases lx team0) ----------
    #pragma unroll 1
    for (int round = 0; round < 8; ++round) {
      if (wv == round) {
        #pragma unroll
        for (int m2 = 0; m2 < 2; ++m2)
          #pragma unroll
          for (int nt = 0; nt < 8; ++nt)
            #pragma unroll
            for (int r = 0; r < 4; ++r) {
              int cc = m2 * 16 + lg * 4 + r;   // C/D: col=l15, row=lg*4+r
              int kk = nt * 16 + l15;
              if (round == 0) yv[cc * 128 + kk]  = yacc[m2][nt][r];
              else            yv[cc * 128 + kk] += yacc[m2][nt][r];
            }
      }
      __syncthreads();
    }
    // yv now holds y for this iter; next iter's prologue consumes it directly
  }

  // ---------- final: o = squash(y2·W) -> out ----------
  float sreg;
  {
    int c = t >> 4, d = t & 15;
    float acc = 0.f;
    #pragma unroll 8
    for (int k = 0; k < KD; ++k) acc += yv[c * KD + k] * W[k * 512 + c * 16 + d];
    sreg = acc;
  }
  sarr[t] = sreg;
  __syncthreads();
  {
    int c = t >> 4;
    float s2 = 1e-7f;
    #pragma unroll
    for (int dd = 0; dd < 16; ++dd) { float v = sarr[c * 16 + dd]; s2 += v * v; }
    out[(size_t)b * 512 + t] = (sqrtf(s2) / (0.5f + s2)) * sreg;
  }
}

extern "C" void kernel_launch(void* const* d_in, const int* in_sizes, int n_in,
                              void* d_out, int out_size, void* d_ws, size_t ws_size,
                              hipStream_t stream) {
  const float* x = (const float*)d_in[0];   // (128, 2048, 128) fp32
  const float* W = (const float*)d_in[1];   // (128, 512) fp32
  float* out = (float*)d_out;               // (128, 32, 16) fp32
  char* ws = (char*)d_ws;
  // ws: [Sp 1MB][xs 64MB] = 65MB
  float* Sp = (float*)ws;
  short* xs = (short*)(ws + (1u << 20));

  prep_k <<<dim3(2048), dim3(256), 0, stream>>>(x, xs, Sp);
  route_k<<<dim3(128),  dim3(512), 0, stream>>>(xs, W, Sp, out);
}